// Round 5
// baseline (192.209 us; speedup 1.0000x reference)
//
#include <hip/hip_runtime.h>

typedef _Float16 half8_t __attribute__((ext_vector_type(8)));
typedef _Float16 half4_t __attribute__((ext_vector_type(4)));
typedef float    float4_t __attribute__((ext_vector_type(4)));

// ---------------- ws layout ----------------
// [0, 55296)        WqkvT  f16  [288][96]   WqkvT[f][k] = W_qkv[k][f]
// [55296, 73728)    WoutT  f16  [96][96]    WoutT[f][k] = W_out[k][f]
// [73728, 77824)    biasT  f32  [4][16][16] biasT[m][j][i] = bias_variant_m[i][j]
#define WOUTT_OFF_H 27648   // in f16 elements
#define BIAST_OFF_B 73728   // bytes

__global__ void prep_kernel(const float* __restrict__ Wqkv,
                            const float* __restrict__ Wout,
                            const float* __restrict__ pos,
                            _Float16* __restrict__ wqkvT,
                            _Float16* __restrict__ woutT,
                            float* __restrict__ biasT) {
  int idx = blockIdx.x * 256 + threadIdx.x;
  if (idx < 288 * 96) {
    int f = idx / 96, k = idx % 96;
    wqkvT[idx] = (_Float16)Wqkv[k * 288 + f];
  } else if (idx < 288 * 96 + 96 * 96) {
    int t = idx - 288 * 96;
    int f = t / 96, k = t % 96;
    woutT[t] = (_Float16)Wout[k * 96 + f];
  } else if (idx < 288 * 96 + 96 * 96 + 1024) {
    int t = idx - (288 * 96 + 96 * 96);
    int m = t >> 8, j = (t >> 4) & 15, i = t & 15;   // store [j][i] = bias[i][j]
    int xi = i >> 2, yi = i & 3, xj = j >> 2, yj = j & 3;
    // bias[i][j] = pos[idx[j] - idx[i] + 3]  (key minus query)
    float v = pos[(xj - xi + 3) * 7 + (yj - yi + 3)];
    if ((m & 1) && ((i >= 8) != (j >= 8))) v -= 1e9f;      // ul mask (last window row)
    if ((m & 2) && ((yi >= 2) != (yj >= 2))) v -= 1e9f;    // lr mask (last window col)
    biasT[t] = v;
  }
}

static __device__ __forceinline__ half4_t pack4(float4_t a) {
  half4_t h;
  h[0] = (_Float16)a[0]; h[1] = (_Float16)a[1];
  h[2] = (_Float16)a[2]; h[3] = (_Float16)a[3];
  return h;
}

// All-register pipeline: for 16x16x16f16, A(row=l15,k=4g+r), B(col=l15,k=4g+r),
// D(col=l15,row=4g+r). GEMM1's D tiles (lane=token / lane=vfeat) are DIRECTLY
// the A/B operands of QK^T and PV; PV's D is directly GEMM3's B. Zero LDS.
__global__ __launch_bounds__(256, 4)
void swin_fused(const float* __restrict__ x,
                const _Float16* __restrict__ wqkvT,
                const _Float16* __restrict__ woutT,
                const float* __restrict__ biasT,
                const float* __restrict__ b_out,
                float* __restrict__ out) {
  const int tid  = threadIdx.x;
  const int wave = tid >> 6;
  const int lane = tid & 63;
  const int l15  = lane & 15;
  const int g    = (lane >> 4) & 3;
  const int ty = l15 >> 2, tx = l15 & 3;

  const int blk   = blockIdx.x;
  const int batch = blk / 196;
  const int wid   = (blk % 196) * 4 + wave;   // this wave's window
  const int wrow = wid / 28, wcol = wid % 28;

  // token position with cyclic shift folded in (same addr used for the store)
  int p = wrow * 4 + ty + 2; if (p >= 112) p -= 112;
  int q = wcol * 4 + tx + 2; if (q >= 112) q -= 112;
  const float* xr = x + (((size_t)batch * 112 + p) * 112 + q) * 96 + g * 8;

  // ---- batch-issue all global x loads (one latency wait per wave)
  float4_t xa[3], xb[3];
#pragma unroll
  for (int kt = 0; kt < 3; ++kt) {
    xa[kt] = *(const float4_t*)(xr + kt * 32);
    xb[kt] = *(const float4_t*)(xr + kt * 32 + 4);
  }
  // bias loads issued early (used only in attn)
  const int var = (wrow == 27 ? 1 : 0) + (wcol == 27 ? 2 : 0);
  const float* bt = biasT + var * 256 + g * 64 + l15;   // [var][j=4g+r][i=l15]
  const float b0 = bt[0], b1 = bt[16], b2 = bt[32], b3 = bt[48];

  half8_t xf[3];   // B of W@x^T (col=tok l15, k=8g+..) AND A of x@Wv (row=tok l15)
#pragma unroll
  for (int kt = 0; kt < 3; ++kt) {
    half8_t h;
    h[0] = (_Float16)xa[kt][0]; h[1] = (_Float16)xa[kt][1];
    h[2] = (_Float16)xa[kt][2]; h[3] = (_Float16)xa[kt][3];
    h[4] = (_Float16)xb[kt][0]; h[5] = (_Float16)xb[kt][1];
    h[6] = (_Float16)xb[kt][2]; h[7] = (_Float16)xb[kt][3];
    xf[kt] = h;
  }

  // ---- GEMM1 q,k tiles: D = WqkvT_slice @ x^T (row=feat, col=tok)
  // per-lane D: col=tok l15, feats f*16+4g+{0..3}  -> qk16[f]
  half4_t qk16[12];   // f 0..5 = q feats 0..95, f 6..11 = k feats 0..95
#pragma unroll
  for (int f = 0; f < 12; ++f) {
    const _Float16* wp = &wqkvT[(f * 16 + l15) * 96 + g * 8];
    half8_t w0 = *(const half8_t*)(wp);
    half8_t w1 = *(const half8_t*)(wp + 32);
    half8_t w2 = *(const half8_t*)(wp + 64);
    float4_t acc = {0.f, 0.f, 0.f, 0.f};
    acc = __builtin_amdgcn_mfma_f32_16x16x32_f16(w0, xf[0], acc, 0, 0, 0);
    acc = __builtin_amdgcn_mfma_f32_16x16x32_f16(w1, xf[1], acc, 0, 0, 0);
    acc = __builtin_amdgcn_mfma_f32_16x16x32_f16(w2, xf[2], acc, 0, 0, 0);
    qk16[f] = pack4(acc);
  }
  // ---- GEMM1 v tiles: D = x @ Wv_slice (row=tok, col=vfeat)
  // per-lane D: col=vfeat l15, toks 4g+{0..3} -> A operand of PV (k=tokens)
  half4_t vt16[6];
#pragma unroll
  for (int f = 12; f < 18; ++f) {
    const _Float16* wp = &wqkvT[(f * 16 + l15) * 96 + g * 8];
    half8_t w0 = *(const half8_t*)(wp);
    half8_t w1 = *(const half8_t*)(wp + 32);
    half8_t w2 = *(const half8_t*)(wp + 64);
    float4_t acc = {0.f, 0.f, 0.f, 0.f};
    acc = __builtin_amdgcn_mfma_f32_16x16x32_f16(xf[0], w0, acc, 0, 0, 0);
    acc = __builtin_amdgcn_mfma_f32_16x16x32_f16(xf[1], w1, acc, 0, 0, 0);
    acc = __builtin_amdgcn_mfma_f32_16x16x32_f16(xf[2], w2, acc, 0, 0, 0);
    vt16[f - 12] = pack4(acc);
  }

  // ---- attention (all registers)
  half4_t ao[6];   // attn-out: per-lane col=tok l15, vfeats kt*16+4g+{0..3}
#pragma unroll
  for (int h = 0; h < 3; ++h) {
    // dots^T = K @ Q^T : two chained 16x16x16 (16 feats each)
    float4_t dd = {0.f, 0.f, 0.f, 0.f};
    dd = __builtin_amdgcn_mfma_f32_16x16x16f16(qk16[6 + 2 * h], qk16[2 * h],     dd, 0, 0, 0);
    dd = __builtin_amdgcn_mfma_f32_16x16x16f16(qk16[7 + 2 * h], qk16[2 * h + 1], dd, 0, 0, 0);
    const float scale = 0.17677669529663687f;  // 32^-0.5
    float dv0 = dd[0] * scale + b0;
    float dv1 = dd[1] * scale + b1;
    float dv2 = dd[2] * scale + b2;
    float dv3 = dd[3] * scale + b3;
    // softmax over keys j (4 regs + lane-groups 16/32): query col i fixed per lane
    float mx = fmaxf(fmaxf(dv0, dv1), fmaxf(dv2, dv3));
    mx = fmaxf(mx, __shfl_xor(mx, 16, 64));
    mx = fmaxf(mx, __shfl_xor(mx, 32, 64));
    float p0 = __expf(dv0 - mx), p1 = __expf(dv1 - mx);
    float p2 = __expf(dv2 - mx), p3 = __expf(dv3 - mx);
    float s = p0 + p1 + p2 + p3;
    s += __shfl_xor(s, 16, 64);
    s += __shfl_xor(s, 32, 64);
    float r = 1.0f / s;
    half4_t pb;   // P^T: B operand (col=query l15, k=key 4g+{0..3})
    pb[0] = (_Float16)(p0 * r); pb[1] = (_Float16)(p1 * r);
    pb[2] = (_Float16)(p2 * r); pb[3] = (_Float16)(p3 * r);
#pragma unroll
    for (int db = 0; db < 2; ++db) {
      // out^T[16-block] = v^T @ P^T : A = vt16[2h+db] (direct), B = pb
      float4_t o = {0.f, 0.f, 0.f, 0.f};
      o = __builtin_amdgcn_mfma_f32_16x16x16f16(vt16[2 * h + db], pb, o, 0, 0, 0);
      ao[2 * h + db] = pack4(o);
    }
  }

  // ---- GEMM3: y^T = WoutT @ ao^T, six chained 16x16x16; B = ao (direct)
  {
    float* orow = out + (((size_t)batch * 112 + p) * 112 + q) * 96;
#pragma unroll
    for (int mt = 0; mt < 6; ++mt) {
      float4_t acc = {0.f, 0.f, 0.f, 0.f};
#pragma unroll
      for (int kt = 0; kt < 6; ++kt) {
        // A: row=outfeat mt*16+l15, k=attnfeat kt*16+4g+{0..3}
        half4_t wo = *(const half4_t*)&woutT[(mt * 16 + l15) * 96 + kt * 16 + g * 4];
        acc = __builtin_amdgcn_mfma_f32_16x16x16f16(wo, ao[kt], acc, 0, 0, 0);
      }
      float4_t bb = *(const float4_t*)&b_out[mt * 16 + g * 4];
      acc[0] += bb[0]; acc[1] += bb[1]; acc[2] += bb[2]; acc[3] += bb[3];
      *(float4_t*)&orow[mt * 16 + g * 4] = acc;
    }
  }
}

extern "C" void kernel_launch(void* const* d_in, const int* in_sizes, int n_in,
                              void* d_out, int out_size, void* d_ws, size_t ws_size,
                              hipStream_t stream) {
  const float* x    = (const float*)d_in[0];
  const float* Wqkv = (const float*)d_in[1];
  const float* pos  = (const float*)d_in[2];
  const float* Wout = (const float*)d_in[3];
  const float* bout = (const float*)d_in[4];
  char* ws = (char*)d_ws;
  _Float16* wqkvT = (_Float16*)ws;
  _Float16* woutT = ((_Float16*)ws) + WOUTT_OFF_H;
  float* biasT = (float*)(ws + BIAST_OFF_B);

  prep_kernel<<<148, 256, 0, stream>>>(Wqkv, Wout, pos, wqkvT, woutT, biasT);
  swin_fused<<<6272, 256, 0, stream>>>(x, wqkvT, woutT, biasT, bout, (float*)d_out);
}

// Round 6
// 118.782 us; speedup vs baseline: 1.6182x; 1.6182x over previous
//
#include <hip/hip_runtime.h>

typedef _Float16 half8_t __attribute__((ext_vector_type(8)));
typedef _Float16 half4_t __attribute__((ext_vector_type(4)));
typedef float    float4_t __attribute__((ext_vector_type(4)));

// ---------------- ws layout ----------------
// [0, 55296)        WqkvT  f16  [288][96]   WqkvT[f][k] = W_qkv[k][f]
// [55296, 73728)    WoutT  f16  [96][96]    WoutT[f][k] = W_out[k][f]
// [73728, 77824)    biasT  f32  [4][16][16] biasT[m][j][i] = bias_variant_m[i][j]
#define WOUTT_OFF_H 27648   // in f16 elements
#define BIAST_OFF_B 73728   // bytes

__global__ void prep_kernel(const float* __restrict__ Wqkv,
                            const float* __restrict__ Wout,
                            const float* __restrict__ pos,
                            _Float16* __restrict__ wqkvT,
                            _Float16* __restrict__ woutT,
                            float* __restrict__ biasT) {
  int idx = blockIdx.x * 256 + threadIdx.x;
  if (idx < 288 * 96) {
    int f = idx / 96, k = idx % 96;
    wqkvT[idx] = (_Float16)Wqkv[k * 288 + f];
  } else if (idx < 288 * 96 + 96 * 96) {
    int t = idx - 288 * 96;
    int f = t / 96, k = t % 96;
    woutT[t] = (_Float16)Wout[k * 96 + f];
  } else if (idx < 288 * 96 + 96 * 96 + 1024) {
    int t = idx - (288 * 96 + 96 * 96);
    int m = t >> 8, j = (t >> 4) & 15, i = t & 15;   // store [j][i] = bias[i][j]
    int xi = i >> 2, yi = i & 3, xj = j >> 2, yj = j & 3;
    // bias[i][j] = pos[idx[j] - idx[i] + 3]  (key minus query)
    float v = pos[(xj - xi + 3) * 7 + (yj - yi + 3)];
    if ((m & 1) && ((i >= 8) != (j >= 8))) v -= 1e9f;      // ul mask (last window row)
    if ((m & 2) && ((yi >= 2) != (yj >= 2))) v -= 1e9f;    // lr mask (last window col)
    biasT[t] = v;
  }
}

static __device__ __forceinline__ half4_t pack4(float4_t a) {
  half4_t h;
  h[0] = (_Float16)a[0]; h[1] = (_Float16)a[1];
  h[2] = (_Float16)a[2]; h[3] = (_Float16)a[3];
  return h;
}

// WqkvT staged in LDS (padded stride 104 f16 -> conflict-free b128 reads);
// WoutT fragments hoisted in registers; all intermediates register-resident
// via direct MFMA D->A/B fragment chaining (verified rounds 2-5).
#define WL_STRIDE 104

__global__ __launch_bounds__(256, 2)
void swin_fused(const float* __restrict__ x,
                const _Float16* __restrict__ wqkvT,
                const _Float16* __restrict__ woutT,
                const float* __restrict__ biasT,
                const float* __restrict__ b_out,
                float* __restrict__ out) {
  __shared__ _Float16 wlds[288 * WL_STRIDE];   // 59904 B
  const int tid  = threadIdx.x;
  const int wave = tid >> 6;
  const int lane = tid & 63;
  const int l15  = lane & 15;
  const int g    = (lane >> 4) & 3;
  const int ty = l15 >> 2, tx = l15 & 3;

  const int blk   = blockIdx.x;
  const int batch = blk / 49;
  const int wbase = (blk % 49) * 16 + wave * 4;   // this wave's 4 windows

  // per-window token positions (cyclic shift folded in; reused for stores)
  int pp[4], qq[4];
#pragma unroll
  for (int w = 0; w < 4; ++w) {
    int wid = wbase + w;
    int wrow = wid / 28, wcol = wid % 28;
    int p = wrow * 4 + ty + 2; if (p >= 112) p -= 112;
    int q = wcol * 4 + tx + 2; if (q >= 112) q -= 112;
    pp[w] = p; qq[w] = q;
  }

  // ---- batch-issue ALL x loads first (HBM latency hides under staging+barrier)
  float4_t xa[4][3], xb[4][3];
#pragma unroll
  for (int w = 0; w < 4; ++w) {
    const float* xr = x + (((size_t)batch * 112 + pp[w]) * 112 + qq[w]) * 96 + g * 8;
#pragma unroll
    for (int kt = 0; kt < 3; ++kt) {
      xa[w][kt] = *(const float4_t*)(xr + kt * 32);
      xb[w][kt] = *(const float4_t*)(xr + kt * 32 + 4);
    }
  }

  // ---- hoist WoutT fragments (A of GEMM3): row=outfeat mt*16+l15, k=kt*16+4g..
  half4_t woutf[6][6];
#pragma unroll
  for (int mt = 0; mt < 6; ++mt)
#pragma unroll
    for (int kt = 0; kt < 6; ++kt)
      woutf[mt][kt] = *(const half4_t*)&woutT[(mt * 16 + l15) * 96 + kt * 16 + g * 4];

  // ---- stage WqkvT into LDS (row stride 104: conflict-free fragment reads)
  for (int i = tid; i < 3456; i += 256) {
    int r = i / 12, c = (i % 12) << 3;
    *(half8_t*)&wlds[r * WL_STRIDE + c] = *(const half8_t*)&wqkvT[r * 96 + c];
  }
  __syncthreads();

  // ---- convert x to f16 fragments (frees the f32 copies)
  half8_t xf[4][3];
#pragma unroll
  for (int w = 0; w < 4; ++w)
#pragma unroll
    for (int kt = 0; kt < 3; ++kt) {
      half8_t h;
      h[0] = (_Float16)xa[w][kt][0]; h[1] = (_Float16)xa[w][kt][1];
      h[2] = (_Float16)xa[w][kt][2]; h[3] = (_Float16)xa[w][kt][3];
      h[4] = (_Float16)xb[w][kt][0]; h[5] = (_Float16)xb[w][kt][1];
      h[6] = (_Float16)xb[w][kt][2]; h[7] = (_Float16)xb[w][kt][3];
      xf[w][kt] = h;
    }

  // ---- per-window compute, all intermediates in registers
#pragma unroll
  for (int w = 0; w < 4; ++w) {
    const int wid = wbase + w;
    const int wrow = wid / 28, wcol = wid % 28;
    const int var = (wrow == 27 ? 1 : 0) + (wcol == 27 ? 2 : 0);
    const float* bt = biasT + var * 256 + g * 64 + l15;   // [var][j=4g+r][i=l15]
    const float b0 = bt[0], b1 = bt[16], b2 = bt[32], b3 = bt[48];

    // GEMM1 q,k tiles: D = WqkvT_slice @ x^T (per-lane: col=tok l15, feats 4g+r)
    half4_t qk16[12];
#pragma unroll
    for (int f = 0; f < 12; ++f) {
      const _Float16* wp = &wlds[(f * 16 + l15) * WL_STRIDE + g * 8];
      half8_t w0 = *(const half8_t*)(wp);
      half8_t w1 = *(const half8_t*)(wp + 32);
      half8_t w2 = *(const half8_t*)(wp + 64);
      float4_t acc = {0.f, 0.f, 0.f, 0.f};
      acc = __builtin_amdgcn_mfma_f32_16x16x32_f16(w0, xf[w][0], acc, 0, 0, 0);
      acc = __builtin_amdgcn_mfma_f32_16x16x32_f16(w1, xf[w][1], acc, 0, 0, 0);
      acc = __builtin_amdgcn_mfma_f32_16x16x32_f16(w2, xf[w][2], acc, 0, 0, 0);
      qk16[f] = pack4(acc);
    }
    // GEMM1 v tiles: D = x @ Wv_slice (per-lane: col=vfeat l15, toks 4g+r)
    half4_t vt16[6];
#pragma unroll
    for (int f = 12; f < 18; ++f) {
      const _Float16* wp = &wlds[(f * 16 + l15) * WL_STRIDE + g * 8];
      half8_t w0 = *(const half8_t*)(wp);
      half8_t w1 = *(const half8_t*)(wp + 32);
      half8_t w2 = *(const half8_t*)(wp + 64);
      float4_t acc = {0.f, 0.f, 0.f, 0.f};
      acc = __builtin_amdgcn_mfma_f32_16x16x32_f16(xf[w][0], w0, acc, 0, 0, 0);
      acc = __builtin_amdgcn_mfma_f32_16x16x32_f16(xf[w][1], w1, acc, 0, 0, 0);
      acc = __builtin_amdgcn_mfma_f32_16x16x32_f16(xf[w][2], w2, acc, 0, 0, 0);
      vt16[f - 12] = pack4(acc);
    }

    // attention (registers + lane-group shuffles)
    half4_t ao[6];
#pragma unroll
    for (int h = 0; h < 3; ++h) {
      float4_t dd = {0.f, 0.f, 0.f, 0.f};
      dd = __builtin_amdgcn_mfma_f32_16x16x16f16(qk16[6 + 2 * h], qk16[2 * h],     dd, 0, 0, 0);
      dd = __builtin_amdgcn_mfma_f32_16x16x16f16(qk16[7 + 2 * h], qk16[2 * h + 1], dd, 0, 0, 0);
      const float scale = 0.17677669529663687f;  // 32^-0.5
      float dv0 = dd[0] * scale + b0;
      float dv1 = dd[1] * scale + b1;
      float dv2 = dd[2] * scale + b2;
      float dv3 = dd[3] * scale + b3;
      float mx = fmaxf(fmaxf(dv0, dv1), fmaxf(dv2, dv3));
      mx = fmaxf(mx, __shfl_xor(mx, 16, 64));
      mx = fmaxf(mx, __shfl_xor(mx, 32, 64));
      float p0 = __expf(dv0 - mx), p1 = __expf(dv1 - mx);
      float p2 = __expf(dv2 - mx), p3 = __expf(dv3 - mx);
      float s = p0 + p1 + p2 + p3;
      s += __shfl_xor(s, 16, 64);
      s += __shfl_xor(s, 32, 64);
      float r = 1.0f / s;
      half4_t pb;   // P^T: B operand (col=query l15, k=key 4g+r)
      pb[0] = (_Float16)(p0 * r); pb[1] = (_Float16)(p1 * r);
      pb[2] = (_Float16)(p2 * r); pb[3] = (_Float16)(p3 * r);
#pragma unroll
      for (int db = 0; db < 2; ++db) {
        float4_t o = {0.f, 0.f, 0.f, 0.f};
        o = __builtin_amdgcn_mfma_f32_16x16x16f16(vt16[2 * h + db], pb, o, 0, 0, 0);
        ao[2 * h + db] = pack4(o);
      }
    }

    // GEMM3: y^T = WoutT @ ao^T (A from hoisted regs, B = ao direct); store
    {
      float* orow = out + (((size_t)batch * 112 + pp[w]) * 112 + qq[w]) * 96;
#pragma unroll
      for (int mt = 0; mt < 6; ++mt) {
        float4_t acc = {0.f, 0.f, 0.f, 0.f};
#pragma unroll
        for (int kt = 0; kt < 6; ++kt)
          acc = __builtin_amdgcn_mfma_f32_16x16x16f16(woutf[mt][kt], ao[kt], acc, 0, 0, 0);
        float4_t bb = *(const float4_t*)&b_out[mt * 16 + g * 4];
        acc[0] += bb[0]; acc[1] += bb[1]; acc[2] += bb[2]; acc[3] += bb[3];
        *(float4_t*)&orow[mt * 16 + g * 4] = acc;
      }
    }
  }
}

extern "C" void kernel_launch(void* const* d_in, const int* in_sizes, int n_in,
                              void* d_out, int out_size, void* d_ws, size_t ws_size,
                              hipStream_t stream) {
  const float* x    = (const float*)d_in[0];
  const float* Wqkv = (const float*)d_in[1];
  const float* pos  = (const float*)d_in[2];
  const float* Wout = (const float*)d_in[3];
  const float* bout = (const float*)d_in[4];
  char* ws = (char*)d_ws;
  _Float16* wqkvT = (_Float16*)ws;
  _Float16* woutT = ((_Float16*)ws) + WOUTT_OFF_H;
  float* biasT = (float*)(ws + BIAST_OFF_B);

  prep_kernel<<<148, 256, 0, stream>>>(Wqkv, Wout, pos, wqkvT, woutT, biasT);
  swin_fused<<<1568, 256, 0, stream>>>(x, wqkvT, woutT, biasT, bout, (float*)d_out);
}